// Round 6
// baseline (37.752 us; speedup 1.0000x reference)
//
#include <hip/hip_runtime.h>

#define B_SAMPLES 1024
#define T_LEN     2048
#define NLAG      512
#define ROWW      172   // uint words per Z row; 172%32=12 -> balanced quad spread for b128

typedef _Float16 half8_t __attribute__((ext_vector_type(8)));
typedef float    floatx4 __attribute__((ext_vector_type(4)));

__device__ __forceinline__ int slotP(int k) { return k + (k >> 5); }

// One block (128 thr = 2 waves) per sample. Wave w computes G_v for
// v in [16w, 16w+16] via MFMA with q-outer sliding B-windows.
// Last finishing block reduces the 1024 per-sample partials (fixed order,
// deterministic) and writes the scalar output.
__global__ __launch_bounds__(128) void msd_mfma_kernel(
    const float* __restrict__ alpha, const float* __restrict__ d0p,
    const float* __restrict__ traj, float* __restrict__ partial,
    unsigned int* __restrict__ counter, float* __restrict__ out) {
  const int b   = blockIdx.x;
  const int tid = threadIdx.x;
  const int w   = tid >> 6;
  const int l   = tid & 63;
  const int g   = l >> 4;
  const int p16 = l & 15;

  __shared__ __align__(16) unsigned int Zw[16 * ROWW];  // 11008 B
  __shared__ float Pb[2116];                            // padded prefix sums
  __shared__ float Elds[2][17][16];                     // E(lag) staging
  __shared__ float wred[2];
  __shared__ int   sFlag;

  // zero pad u in [128,172)
  for (int k = tid; k < 16 * 44; k += 128)
    Zw[(k / 44) * ROWW + 128 + (k % 44)] = 0u;

  // stage: float4 = 2 timesteps per load; wave w covers t in [1024w, 1024w+1024)
  const float4* tr4 = reinterpret_cast<const float4*>(traj) + (size_t)b * (T_LEN / 2);
  #pragma unroll
  for (int s = 0; s < 8; ++s) {
    int idx = (w << 9) + (s << 6) + l;
    float4 v4 = tr4[idx];
    int t0 = idx << 1;
    _Float16 hx0 = (_Float16)v4.x, hy0 = (_Float16)v4.y;
    _Float16 hx1 = (_Float16)v4.z, hy1 = (_Float16)v4.w;
    unsigned int wd0 = (unsigned int)__builtin_bit_cast(unsigned short, hx0)
                     | ((unsigned int)__builtin_bit_cast(unsigned short, hy0) << 16);
    unsigned int wd1 = (unsigned int)__builtin_bit_cast(unsigned short, hx1)
                     | ((unsigned int)__builtin_bit_cast(unsigned short, hy1) << 16);
    Zw[(t0 & 15) * ROWW + (t0 >> 4)] = wd0;
    Zw[((t0 + 1) & 15) * ROWW + ((t0 + 1) >> 4)] = wd1;
  }
  __syncthreads();

  // wave 0 only: fp32 prefix sums of |x_t|^2 -> Pb[slotP(0..2048)]
  if (w == 0) {
    const unsigned int* zs = &Zw[2 * l];
    float csum = 0.f;
    #pragma unroll
    for (int i = 0; i < 32; ++i) {
      unsigned int word = zs[(i & 15) * ROWW + (i >> 4)];
      float fx = (float)__builtin_bit_cast(_Float16, (unsigned short)(word & 0xffffu));
      float fy = (float)__builtin_bit_cast(_Float16, (unsigned short)(word >> 16));
      csum = fmaf(fx, fx, fmaf(fy, fy, csum));
    }
    float run = csum;
    #pragma unroll
    for (int dlt = 1; dlt < 64; dlt <<= 1) {
      float tsh = __shfl_up(run, dlt, 64);
      if (l >= dlt) run += tsh;
    }
    float r2 = run - csum;            // exclusive prefix for this lane's chunk
    if (l == 0) Pb[0] = 0.f;
    #pragma unroll
    for (int i = 0; i < 32; ++i) {
      unsigned int word = zs[(i & 15) * ROWW + (i >> 4)];
      float fx = (float)__builtin_bit_cast(_Float16, (unsigned short)(word & 0xffffu));
      float fy = (float)__builtin_bit_cast(_Float16, (unsigned short)(word >> 16));
      r2 = fmaf(fx, fx, fmaf(fy, fy, r2));
      Pb[slotP(32 * l + i + 1)] = r2;
    }
  }

  const unsigned int* zrow = &Zw[p16 * ROWW];
  const int vS = 16 * w;

  floatx4 D[17];
  #pragma unroll
  for (int r = 0; r < 17; ++r) D[r] = (floatx4){0.f, 0.f, 0.f, 0.f};

  #pragma unroll
  for (int q = 0; q < 8; ++q) {
    const unsigned int* wp = zrow + 16 * q + 4 * g + vS;   // 16B-aligned
    uint4 w0 = *reinterpret_cast<const uint4*>(wp);
    uint4 w1 = *reinterpret_cast<const uint4*>(wp + 4);
    uint4 w2 = *reinterpret_cast<const uint4*>(wp + 8);
    uint4 w3 = *reinterpret_cast<const uint4*>(wp + 12);
    uint4 w4 = *reinterpret_cast<const uint4*>(wp + 16);
    unsigned int win[20] = {w0.x, w0.y, w0.z, w0.w,  w1.x, w1.y, w1.z, w1.w,
                            w2.x, w2.y, w2.z, w2.w,  w3.x, w3.y, w3.z, w3.w,
                            w4.x, w4.y, w4.z, w4.w};
    half8_t aq;
    if (w == 0) {
      aq = __builtin_bit_cast(half8_t, w0);   // vS=0: window start IS the A-frag
    } else {
      uint4 aw = *reinterpret_cast<const uint4*>(zrow + 16 * q + 4 * g);
      aq = __builtin_bit_cast(half8_t, aw);
    }
    #pragma unroll
    for (int r = 0; r < 17; ++r) {
      uint4 bw;
      bw.x = win[r]; bw.y = win[r + 1]; bw.z = win[r + 2]; bw.w = win[r + 3];
      half8_t bf = __builtin_bit_cast(half8_t, bw);
      D[r] = __builtin_amdgcn_mfma_f32_16x16x32_f16(aq, bf, D[r], 0, 0, 0);
    }
  }

  // diagonal extraction; stage E(lag) to LDS (no trans work in this loop)
  float prevA = 0.f;
  const int rotb = 4 * g + p16;
  const int idx0 = (l & 48) << 2;

  #pragma unroll
  for (int r = 0; r < 17; ++r) {
    float accA = 0.f, accB = 0.f;
    #pragma unroll
    for (int rr = 0; rr < 4; ++rr) {
      float gv = D[r][rr];
      int src = idx0 | (((rotb + rr) & 15) << 2);
      float got = __builtin_bit_cast(float,
          __builtin_amdgcn_ds_bpermute(src, __builtin_bit_cast(int, gv)));
      bool wrap = (rotb + rr) >= 16;
      accA += wrap ? 0.f : got;
      accB += wrap ? got : 0.f;
    }
    if (r > 0) {
      float E = prevA + accB;
      E += __shfl_xor(E, 16, 64);
      E += __shfl_xor(E, 32, 64);
      if (l < 16) Elds[w][r - 1][p16] = E;   // lag = 16*(vS + r - 1) + p16
    }
    prevA = accA;
  }
  if (w == 1) {   // lag = 512 = diag_0(G_32) from last accA
    float E = prevA;
    E += __shfl_xor(E, 16, 64);
    E += __shfl_xor(E, 32, 64);
    if (l == 0) Elds[1][16][0] = E;
  }
  __syncthreads();   // Pb (wave 0) + Elds visible to all

  // full-width finalize: 4 lags per thread across 128 threads = lags 1..512
  const float Ptot = Pb[slotP(2048)];
  const float aexp = alpha[b];
  const float c4d0 = 4.f * d0p[b];
  float loc = 0.f;
  #pragma unroll
  for (int c = 0; c < 4; ++c) {
    int lag = c * 128 + tid + 1;
    int q16 = lag >> 4, p = lag & 15;
    int wq = q16 >> 4, rr = q16 & 15;
    if (lag == 512) { wq = 1; rr = 16; p = 0; }
    float E  = Elds[wq][rr][p];
    float Pl = Pb[slotP(lag)];
    int mm   = 2048 - lag;
    float Pr = Pb[slotP(mm)];
    float S2  = Pr + (Ptot - Pl);
    float msd = fmaxf((S2 - 2.f * E) / (float)mm, 0.f);
    float theo = c4d0 * __builtin_exp2f(aexp * __builtin_log2f((float)lag));
    float dd = 0.69314718f * (__builtin_log2f(theo + 1e-8f) - __builtin_log2f(msd + 1e-8f));
    loc = fmaf(dd, dd, loc);
  }

  // block reduce 128 threads -> partial[b]
  #pragma unroll
  for (int dlt = 1; dlt < 64; dlt <<= 1) loc += __shfl_xor(loc, dlt, 64);
  if (l == 0) wred[w] = loc;
  __syncthreads();
  if (tid == 0) {
    partial[b] = wred[0] + wred[1];
    __threadfence();
    unsigned int old = atomicAdd(counter, 1u);
    sFlag = (old == (unsigned int)(B_SAMPLES - 1)) ? 1 : 0;
  }
  __syncthreads();

  // last block to finish: deterministic fixed-order final reduction
  if (sFlag) {
    __threadfence();
    float s = 0.f;
    #pragma unroll
    for (int i = 0; i < 8; ++i) s += partial[8 * tid + i];
    #pragma unroll
    for (int dlt = 1; dlt < 64; dlt <<= 1) s += __shfl_xor(s, dlt, 64);
    if (l == 0) wred[w] = s;
    __syncthreads();
    if (tid == 0)
      out[0] = (wred[0] + wred[1]) * (1.0f / ((float)B_SAMPLES * (float)NLAG));
  }
}

extern "C" void kernel_launch(void* const* d_in, const int* in_sizes, int n_in,
                              void* d_out, int out_size, void* d_ws, size_t ws_size,
                              hipStream_t stream) {
  const float* alpha = (const float*)d_in[0];
  const float* d0p   = (const float*)d_in[1];
  const float* traj  = (const float*)d_in[2];
  float* out     = (float*)d_out;
  float* partial = (float*)d_ws;                                   // 1024 floats
  unsigned int* counter = (unsigned int*)((char*)d_ws + 4096);     // 1 uint

  hipMemsetAsync(counter, 0, 4, stream);
  msd_mfma_kernel<<<B_SAMPLES, 128, 0, stream>>>(alpha, d0p, traj, partial, counter, out);
}

// Round 7
// 15.899 us; speedup vs baseline: 2.3744x; 2.3744x over previous
//
#include <hip/hip_runtime.h>

#define B_SAMPLES 1024
#define T_LEN     2048
#define NLAG      512
#define ROWW      172   // uint words per Z row; 172%32=12 -> balanced quad spread for b128

typedef _Float16 half8_t __attribute__((ext_vector_type(8)));
typedef float    floatx4 __attribute__((ext_vector_type(4)));

__device__ __forceinline__ int slotP(int k) { return k + (k >> 5); }

// One block (256 thr = 4 waves) per sample. Wave w computes G_v for
// v in [8w, 8w+8] via MFMA with q-outer sliding B-windows (D[9] accums).
__global__ __launch_bounds__(256) void msd_mfma_kernel(
    const float* __restrict__ alpha, const float* __restrict__ d0p,
    const float* __restrict__ traj, float* __restrict__ partial) {
  const int b   = blockIdx.x;
  const int tid = threadIdx.x;
  const int w   = tid >> 6;
  const int l   = tid & 63;
  const int g   = l >> 4;
  const int p16 = l & 15;

  __shared__ __align__(16) unsigned int Zw[16 * ROWW];  // 11008 B
  __shared__ float Pb[2116];                            // padded prefix sums
  __shared__ float Elds[33][16];                        // E(lag): [lag>>4][lag&15]; [32][0]=lag512
  __shared__ float wred[4];

  // zero pad u in [128,172)
  for (int k = tid; k < 16 * 44; k += 256)
    Zw[(k / 44) * ROWW + 128 + (k % 44)] = 0u;

  // stage: wave w covers t in [512w, 512w+512), coalesced float2 loads
  const float2* tr = reinterpret_cast<const float2*>(traj) + (size_t)b * T_LEN;
  #pragma unroll
  for (int s = 0; s < 8; ++s) {
    int t = (w << 9) + (s << 6) + l;
    float2 v2 = tr[t];
    _Float16 hx = (_Float16)v2.x;
    _Float16 hy = (_Float16)v2.y;
    unsigned int word = (unsigned int)__builtin_bit_cast(unsigned short, hx)
                      | ((unsigned int)__builtin_bit_cast(unsigned short, hy) << 16);
    Zw[(t & 15) * ROWW + (t >> 4)] = word;
  }
  __syncthreads();

  // wave 0 only: fp32 prefix sums of |x_t|^2 -> Pb[slotP(0..2048)]
  if (w == 0) {
    const unsigned int* zs = &Zw[2 * l];
    float csum = 0.f;
    #pragma unroll
    for (int i = 0; i < 32; ++i) {
      unsigned int word = zs[(i & 15) * ROWW + (i >> 4)];
      float fx = (float)__builtin_bit_cast(_Float16, (unsigned short)(word & 0xffffu));
      float fy = (float)__builtin_bit_cast(_Float16, (unsigned short)(word >> 16));
      csum = fmaf(fx, fx, fmaf(fy, fy, csum));
    }
    float run = csum;
    #pragma unroll
    for (int dlt = 1; dlt < 64; dlt <<= 1) {
      float tsh = __shfl_up(run, dlt, 64);
      if (l >= dlt) run += tsh;
    }
    float r2 = run - csum;            // exclusive prefix for this lane's chunk
    if (l == 0) Pb[0] = 0.f;
    #pragma unroll
    for (int i = 0; i < 32; ++i) {
      unsigned int word = zs[(i & 15) * ROWW + (i >> 4)];
      float fx = (float)__builtin_bit_cast(_Float16, (unsigned short)(word & 0xffffu));
      float fy = (float)__builtin_bit_cast(_Float16, (unsigned short)(word >> 16));
      r2 = fmaf(fx, fx, fmaf(fy, fy, r2));
      Pb[slotP(32 * l + i + 1)] = r2;
    }
  }

  const unsigned int* zrow = &Zw[p16 * ROWW];
  const int vS = 8 * w;

  floatx4 D[9];
  #pragma unroll
  for (int r = 0; r < 9; ++r) D[r] = (floatx4){0.f, 0.f, 0.f, 0.f};

  #pragma unroll
  for (int q = 0; q < 8; ++q) {
    const unsigned int* wp = zrow + 16 * q + 4 * g + vS;   // 16B-aligned (vS%4==0)
    uint4 w0 = *reinterpret_cast<const uint4*>(wp);
    uint4 w1 = *reinterpret_cast<const uint4*>(wp + 4);
    uint4 w2 = *reinterpret_cast<const uint4*>(wp + 8);
    unsigned int win[12] = {w0.x, w0.y, w0.z, w0.w,  w1.x, w1.y, w1.z, w1.w,
                            w2.x, w2.y, w2.z, w2.w};
    uint4 aw = *reinterpret_cast<const uint4*>(zrow + 16 * q + 4 * g);
    half8_t aq = __builtin_bit_cast(half8_t, aw);
    #pragma unroll
    for (int r = 0; r < 9; ++r) {
      uint4 bw;
      bw.x = win[r]; bw.y = win[r + 1]; bw.z = win[r + 2]; bw.w = win[r + 3];
      half8_t bf = __builtin_bit_cast(half8_t, bw);
      D[r] = __builtin_amdgcn_mfma_f32_16x16x32_f16(aq, bf, D[r], 0, 0, 0);
    }
  }

  // diagonal extraction; stage E(lag) to LDS
  float prevA = 0.f;
  const int rotb = 4 * g + p16;
  const int idx0 = (l & 48) << 2;

  #pragma unroll
  for (int r = 0; r < 9; ++r) {
    float accA = 0.f, accB = 0.f;
    #pragma unroll
    for (int rr = 0; rr < 4; ++rr) {
      float gv = D[r][rr];
      int src = idx0 | (((rotb + rr) & 15) << 2);
      float got = __builtin_bit_cast(float,
          __builtin_amdgcn_ds_bpermute(src, __builtin_bit_cast(int, gv)));
      bool wrap = (rotb + rr) >= 16;
      accA += wrap ? 0.f : got;
      accB += wrap ? got : 0.f;
    }
    if (r > 0) {
      float E = prevA + accB;
      E += __shfl_xor(E, 16, 64);
      E += __shfl_xor(E, 32, 64);
      if (l < 16) Elds[vS + r - 1][p16] = E;   // lag = 16*(vS+r-1) + p16
    }
    prevA = accA;
  }
  if (w == 3) {   // lag = 512 = diag_0(G_32) from final accA
    float E = prevA;
    E += __shfl_xor(E, 16, 64);
    E += __shfl_xor(E, 32, 64);
    if (l == 0) Elds[32][0] = E;
  }
  __syncthreads();   // Pb (wave 0) + Elds visible to all

  // full-width finalize: 2 lags per thread across 256 threads = lags 1..512
  const float Ptot = Pb[slotP(2048)];
  const float aexp = alpha[b];
  const float c4d0 = 4.f * d0p[b];
  float loc = 0.f;
  #pragma unroll
  for (int c = 0; c < 2; ++c) {
    int lag = c * 256 + tid + 1;
    float E  = Elds[lag >> 4][lag & 15];
    float Pl = Pb[slotP(lag)];
    int mm   = 2048 - lag;
    float Pr = Pb[slotP(mm)];
    float S2  = Pr + (Ptot - Pl);
    float msd = fmaxf((S2 - 2.f * E) / (float)mm, 0.f);
    float theo = c4d0 * __builtin_exp2f(aexp * __builtin_log2f((float)lag));
    float dd = 0.69314718f * (__builtin_log2f(theo + 1e-8f) - __builtin_log2f(msd + 1e-8f));
    loc = fmaf(dd, dd, loc);
  }

  // block reduce 256 threads -> partial[b] (fixed order, deterministic)
  #pragma unroll
  for (int dlt = 1; dlt < 64; dlt <<= 1) loc += __shfl_xor(loc, dlt, 64);
  if (l == 0) wred[w] = loc;
  __syncthreads();
  if (tid == 0) partial[b] = (wred[0] + wred[1]) + (wred[2] + wred[3]);
}

__global__ __launch_bounds__(256) void reduce_kernel(
    const float* __restrict__ partial, float* __restrict__ out) {
  __shared__ float wsum[4];
  float acc = 0.f;
  for (int i = threadIdx.x; i < B_SAMPLES; i += 256) acc += partial[i];
  for (int off = 32; off > 0; off >>= 1) acc += __shfl_down(acc, off, 64);
  const int wid  = threadIdx.x >> 6;
  const int lane = threadIdx.x & 63;
  if (lane == 0) wsum[wid] = acc;
  __syncthreads();
  if (threadIdx.x == 0) {
    float t = wsum[0] + wsum[1] + wsum[2] + wsum[3];
    out[0] = t * (1.0f / ((float)B_SAMPLES * (float)NLAG));
  }
}

extern "C" void kernel_launch(void* const* d_in, const int* in_sizes, int n_in,
                              void* d_out, int out_size, void* d_ws, size_t ws_size,
                              hipStream_t stream) {
  const float* alpha = (const float*)d_in[0];
  const float* d0p   = (const float*)d_in[1];
  const float* traj  = (const float*)d_in[2];
  float* out     = (float*)d_out;
  float* partial = (float*)d_ws;   // 1024 floats

  msd_mfma_kernel<<<B_SAMPLES, 256, 0, stream>>>(alpha, d0p, traj, partial);
  reduce_kernel<<<1, 256, 0, stream>>>(partial, out);
}